// Round 1
// baseline (178.649 us; speedup 1.0000x reference)
//
#include <hip/hip_runtime.h>
#include <hip/hip_bf16.h>

// compute_pairwise_term fused kernel.
// Input: mask_logits [N=64, 1, H=256, W=256] fp32.
// Output: [N, 8, H, W] fp32, tap order row-major (i,j) skipping center,
// offsets dy=2i-2, dx=2j-2 (dilation=2, pad=2).
//
// Identities used:
//   log_sigmoid(x)  = min(x,0) - log1p(exp(-|x|))
//   log_sigmoid(-x) = log_sigmoid(x) - x
//   OOB tap (zero-padded AFTER log_sigmoid): fg_u=bg_u=0
//   logaddexp(a,b)  = max(a,b) + log1p(exp(-|a-b|))

#define N_IMG 64
#define H_DIM 256
#define W_DIM 256

__device__ __forceinline__ float log_sig(float x) {
    // min(x,0) - log1p(exp(-|x|)); fast-math variants are fine at 6e-2 abs tol
    float t = __expf(-fabsf(x));
    return fminf(x, 0.0f) - __logf(1.0f + t);
}

__global__ __launch_bounds__(256) void pairwise_term_kernel(
        const float* __restrict__ x, float* __restrict__ out) {
    const int idx = blockIdx.x * blockDim.x + threadIdx.x;  // n*H*W + h*W + w
    const int total = N_IMG * H_DIM * W_DIM;
    if (idx >= total) return;

    const int w = idx & (W_DIM - 1);
    const int h = (idx >> 8) & (H_DIM - 1);
    const int n = idx >> 16;

    const float xc = x[idx];
    const float lf = log_sig(xc);
    const float lb = lf - xc;

    // tap offsets, row-major kernel order skipping center
    const int dy[8] = {-2, -2, -2,  0, 0,  2, 2, 2};
    const int dx[8] = {-2,  0,  2, -2, 2, -2, 0, 2};

    float* outp = out + (size_t)n * 8 * H_DIM * W_DIM + h * W_DIM + w;

#pragma unroll
    for (int t = 0; t < 8; ++t) {
        const int hh = h + dy[t];
        const int ww = w + dx[t];
        float lf_t = 0.0f, lb_t = 0.0f;
        if ((unsigned)hh < H_DIM && (unsigned)ww < W_DIM) {
            const float xt = x[idx + dy[t] * W_DIM + dx[t]];
            lf_t = log_sig(xt);
            lb_t = lf_t - xt;
        }
        const float a = lf + lf_t;
        const float b = lb + lb_t;
        const float m = fmaxf(a, b);
        const float r = m + __logf(1.0f + __expf(-fabsf(a - b)));
        outp[(size_t)t * H_DIM * W_DIM] = -r;
    }
}

extern "C" void kernel_launch(void* const* d_in, const int* in_sizes, int n_in,
                              void* d_out, int out_size, void* d_ws, size_t ws_size,
                              hipStream_t stream) {
    const float* x = (const float*)d_in[0];
    float* out = (float*)d_out;
    const int total = N_IMG * H_DIM * W_DIM;
    const int block = 256;
    const int grid = (total + block - 1) / block;
    pairwise_term_kernel<<<grid, block, 0, stream>>>(x, out);
}

// Round 6
// 154.618 us; speedup vs baseline: 1.1554x; 1.1554x over previous
//
#include <hip/hip_runtime.h>
#include <hip/hip_bf16.h>

// compute_pairwise_term, fused + vectorized.
// Input:  mask_logits [N=64, 1, H=256, W=256] fp32
// Output: [N, 8, H, W] fp32; tap t at (dy,dx) = (2*(t_row)-2, 2*(t_col)-2),
//         row-major kernel order with center removed; dilation=2, pad=2.
//
// Identity: with lf = log_sigmoid(x), lb = lf - x,
//   -logaddexp(lf_c+lf_t, lb_c+lb_t) = log_sigmoid(x_c + x_t) - lf_c - lf_t
// OOB taps (zero-padded after log_sigmoid) give exactly 0.

#define NI 64
#define H_DIM 256
#define W_DIM 256

typedef float f32x2 __attribute__((ext_vector_type(2)));
typedef float f32x4 __attribute__((ext_vector_type(4)));

__device__ __forceinline__ float log_sig(float v) {
    // log_sigmoid(v) = min(v,0) - log1p(exp(-|v|))
    return fminf(v, 0.0f) - __logf(1.0f + __expf(-fabsf(v)));
}

__global__ __launch_bounds__(256) void pairwise_term_v2(
        const float* __restrict__ x, float* __restrict__ out) {
    const int tid = blockIdx.x * blockDim.x + threadIdx.x;  // one thread = 4 px
    const int w4 = (tid & 63) << 2;          // W/4 = 64 groups per row
    const int h  = (tid >> 6) & (H_DIM - 1);
    const int n  = tid >> 14;                // 64*256*64 threads total

    const float* img = x + (size_t)n * (H_DIM * W_DIM);

    // Neighborhood: rows {h-2, h, h+2} x cols [w4-2, w4+5]  (8 cols)
    float xv[3][8];
    float lfv[3][8];
    bool  rowv[3];

#pragma unroll
    for (int r = 0; r < 3; ++r) {
        const int hh = h + 2 * (r - 1);
        rowv[r] = (unsigned)hh < H_DIM;
        const float* rp = img + (size_t)(rowv[r] ? hh : h) * W_DIM;
        // clamped, naturally-aligned loads (even col index -> 8B aligned)
        const int lc = (w4 == 0) ? 0 : w4 - 2;
        const int rc = (w4 == W_DIM - 4) ? W_DIM - 2 : w4 + 4;
        const f32x2 a = *reinterpret_cast<const f32x2*>(rp + lc);
        const f32x4 b = *reinterpret_cast<const f32x4*>(rp + w4);
        const f32x2 c = *reinterpret_cast<const f32x2*>(rp + rc);
        xv[r][0] = a.x; xv[r][1] = a.y;
        xv[r][2] = b.x; xv[r][3] = b.y; xv[r][4] = b.z; xv[r][5] = b.w;
        xv[r][6] = c.x; xv[r][7] = c.y;
#pragma unroll
        for (int cc = 0; cc < 8; ++cc) lfv[r][cc] = log_sig(xv[r][cc]);
    }

    bool colv[8];
#pragma unroll
    for (int cc = 0; cc < 8; ++cc) {
        colv[cc] = (unsigned)(w4 - 2 + cc) < W_DIM;
    }

    // taps (row-major, center removed): r index into {h-2,h,h+2}, col offset
    const int tr[8]  = {0, 0, 0, 1, 1, 2, 2, 2};
    const int tco[8] = {0, 2, 4, 0, 4, 0, 2, 4};

    float* op = out + ((size_t)n * 8 * H_DIM + h) * W_DIM + w4;

#pragma unroll
    for (int t = 0; t < 8; ++t) {
        const int r  = tr[t];
        const int co = tco[t];
        float res[4];
#pragma unroll
        for (int p = 0; p < 4; ++p) {
            const int ci = p + co;                 // tap col in [0,8)
            const float s = xv[1][p + 2] + xv[r][ci];
            const float v = log_sig(s) - lfv[1][p + 2] - lfv[r][ci];
            res[p] = (rowv[r] && colv[ci]) ? v : 0.0f;
        }
        f32x4 vec;
        vec.x = res[0]; vec.y = res[1]; vec.z = res[2]; vec.w = res[3];
        __builtin_nontemporal_store(
            vec, reinterpret_cast<f32x4*>(op + (size_t)t * (H_DIM * W_DIM)));
    }
}

extern "C" void kernel_launch(void* const* d_in, const int* in_sizes, int n_in,
                              void* d_out, int out_size, void* d_ws, size_t ws_size,
                              hipStream_t stream) {
    const float* x = (const float*)d_in[0];
    float* out = (float*)d_out;
    const int total_threads = NI * H_DIM * W_DIM / 4;   // 1,048,576
    const int block = 256;
    const int grid = total_threads / block;             // 4096
    pairwise_term_v2<<<grid, block, 0, stream>>>(x, out);
}

// Round 7
// 152.365 us; speedup vs baseline: 1.1725x; 1.0148x over previous
//
#include <hip/hip_runtime.h>
#include <hip/hip_bf16.h>

// compute_pairwise_term, fused + vectorized, 8 px/thread, plain f32x4 stores.
// Input:  mask_logits [N=64, 1, H=256, W=256] fp32
// Output: [N, 8, H, W] fp32; taps row-major, center removed, dilation=2, pad=2.
//
// Identity: with lf = log_sigmoid(x), lb = lf - x,
//   -logaddexp(lf_c+lf_t, lb_c+lb_t) = log_sigmoid(x_c + x_t) - lf_c - lf_t
// OOB taps (zero-padded after log_sigmoid in the reference) give exactly 0.

#define NI 64
#define H_DIM 256
#define W_DIM 256

typedef float f32x4 __attribute__((ext_vector_type(4)));

__device__ __forceinline__ float log_sig(float v) {
    // log_sigmoid(v) = min(v,0) - log1p(exp(-|v|))
    return fminf(v, 0.0f) - __logf(1.0f + __expf(-fabsf(v)));
}

__global__ __launch_bounds__(256) void pairwise_term_v3(
        const float* __restrict__ x, float* __restrict__ out) {
    const int tid = blockIdx.x * blockDim.x + threadIdx.x;  // 1 thread = 8 px
    const int w8 = (tid & 31) << 3;          // 32 col-groups per row
    const int h  = (tid >> 5) & (H_DIM - 1);
    const int n  = tid >> 13;                // total threads = 64*256*32

    const float* img = x + (size_t)n * (H_DIM * W_DIM);

    // Neighborhood: rows {h-2, h, h+2} x cols [w8-4, w8+11] (16 cols loaded,
    // cols c=2..13 i.e. w8-2..w8+9 actually used; edge loads clamped in-range,
    // garbage values masked out by validity below).
    float xr[3][16];
    float lf[3][12];   // log_sig for c = 2..13  (index c-2)
    bool  rowv[3];

#pragma unroll
    for (int r = 0; r < 3; ++r) {
        const int hh = h + 2 * (r - 1);
        rowv[r] = (unsigned)hh < H_DIM;
        const float* rp = img + (size_t)(rowv[r] ? hh : h) * W_DIM;
#pragma unroll
        for (int q = 0; q < 4; ++q) {
            int base = w8 - 4 + 4 * q;
            base = base < 0 ? 0 : (base > W_DIM - 4 ? W_DIM - 4 : base);
            const f32x4 v = *reinterpret_cast<const f32x4*>(rp + base);
            xr[r][4 * q + 0] = v.x; xr[r][4 * q + 1] = v.y;
            xr[r][4 * q + 2] = v.z; xr[r][4 * q + 3] = v.w;
        }
#pragma unroll
        for (int c = 2; c < 14; ++c) lf[r][c - 2] = log_sig(xr[r][c]);
    }

    // taps (row-major kernel order, center removed):
    // t -> (row r in {0,1,2} = {h-2,h,h+2}, dx in {-2,0,2})
    const int tr[8] = {0, 0, 0, 1, 1, 2, 2, 2};
    const int td[8] = {-2, 0, 2, -2, 2, -2, 0, 2};

    float* op = out + ((size_t)n * 8 * H_DIM + h) * W_DIM + w8;

#pragma unroll
    for (int t = 0; t < 8; ++t) {
        const int r  = tr[t];
        const int dx = td[t];
        float res[8];
#pragma unroll
        for (int p = 0; p < 8; ++p) {
            // center col = w8+p (c-index p+4), tap col = w8+p+dx (c-index p+4+dx)
            const float s = xr[1][p + 4] + xr[r][p + 4 + dx];
            const float v = log_sig(s) - lf[1][p + 2] - lf[r][p + 2 + dx];
            const bool ok = rowv[r] && ((unsigned)(w8 + p + dx) < W_DIM);
            res[p] = ok ? v : 0.0f;
        }
        float* tp = op + (size_t)t * (H_DIM * W_DIM);
        f32x4 lo, hi;
        lo.x = res[0]; lo.y = res[1]; lo.z = res[2]; lo.w = res[3];
        hi.x = res[4]; hi.y = res[5]; hi.z = res[6]; hi.w = res[7];
        *reinterpret_cast<f32x4*>(tp)     = lo;
        *reinterpret_cast<f32x4*>(tp + 4) = hi;
    }
}

extern "C" void kernel_launch(void* const* d_in, const int* in_sizes, int n_in,
                              void* d_out, int out_size, void* d_ws, size_t ws_size,
                              hipStream_t stream) {
    const float* x = (const float*)d_in[0];
    float* out = (float*)d_out;
    const int total_threads = NI * H_DIM * (W_DIM / 8);   // 524,288
    const int block = 256;
    const int grid = total_threads / block;               // 2048
    pairwise_term_v3<<<grid, block, 0, stream>>>(x, out);
}